// Round 3
// baseline (145.987 us; speedup 1.0000x reference)
//
#include <hip/hip_runtime.h>
#include <hip/hip_bf16.h>

typedef _Float16 half_t;
typedef __attribute__((ext_vector_type(8))) _Float16 half8;
typedef __attribute__((ext_vector_type(4))) _Float16 half4;
typedef __attribute__((ext_vector_type(4))) float float4v;
typedef __attribute__((ext_vector_type(2))) float float2v;

#define BSZ 8192
#define NT 1024   // 16 waves, grid 256 = 1 block/CU
#define ACTSTR 280  // act stride (halfs): 560B, 16B-aligned
#define XSTR 152    // x stride: 304B
#define ZSTR 40     // z stride: 80B

// ---- dynamic LDS layout (half_t units unless noted) ----
// B-weight ring REMOVED: weights stream HBM/L2 -> VGPR directly (no reuse of
// B within/across waves, so LDS staging was pure FIFO overhead on the LDS pipe).
#define OFF_SX 0
#define OFF_SB0 (OFF_SX + 32 * XSTR)
#define OFF_SB1 (OFF_SB0 + 32 * ACTSTR)
#define OFF_SZ (OFF_SB1 + 32 * ACTSTR)
#define HALFS_TOTAL (OFF_SZ + 32 * ZSTR)   // 24064 halfs = 48128 B
#define OFF_LOG_B (HALFS_TOTAL * 2)
#define OFF_CF_B (OFF_LOG_B + 1024)
#define SMEM_BYTES (OFF_CF_B + 1024)       // 50176 B

__device__ __forceinline__ float elu_fast(float v) {
    return v > 0.f ? v : (__expf(v) - 1.f);
}

// W layout (validated r14): frag-ordered 1KB blocks [e][strip][chunk][512 halfs],
// block[(quad*16+l15)*8+j] = W[n=strip*16+l15][k=chunk*32+quad*8+j]. A lane's
// B fragment is 16B at base + lane*16B -> one coalesced global_load_dwordx4.
// Pass/chunk loops fully unrolled: compiler hoists B loads ahead of the MFMAs.
// r1 LESSON: with __launch_bounds__(1024) the compiler targeted 2 blocks/CU
// (64-VGPR cap) and SPILLED — WRITE_SIZE 4->32MB scratch, all pipes idle.
// r2 LESSON: __launch_bounds__(NT, 4) is a MINIMUM waves/EU — the backend
// still *targeted* 8 waves/EU and kept spilling (VGPR stayed 64). The grid is
// 1 block/CU by construction, so pin the occupancy RANGE:
// amdgpu_waves_per_eu(4,4) -> exactly 4 waves/EU -> 128-VGPR budget, no spill.
template <int EXPP, int NPASS, int CH, int MT, bool ZLAST, int ACT, int DST>
__device__ __forceinline__ void layer_run(
    const half_t* sSrc, int sstr, const half_t* sZ,
    const half_t* __restrict__ W, int NS,
    const float* __restrict__ bias, int biasN, const float* sCf,
    half_t* sDst, float* __restrict__ gOut, int ldg,
    int row0, int strip, int mrow, int lane, int l15, int quad) {
    const size_t estr = (size_t)NS * CH * 512;  // halfs per expert in layout
    const int col = strip * 16 + l15;
    const half_t* wbase = W + (size_t)strip * CH * 512 + lane * 8;
    const half_t* aBase = sSrc + (mrow + l15) * sstr + quad * 8;
    const half_t* zBase = sZ + (mrow + l15) * ZSTR + quad * 8;

    float part[MT][4];
#pragma unroll
    for (int h = 0; h < NPASS; ++h) {
        // per-pass bias in registers (static index, no scratch)
        float bv[EXPP];
#pragma unroll
        for (int e = 0; e < EXPP; ++e)
            bv[e] = bias[(size_t)(h * EXPP + e) * biasN + col];

        float4v acc[EXPP][MT];
#pragma unroll
        for (int e = 0; e < EXPP; ++e)
#pragma unroll
            for (int mt = 0; mt < MT; ++mt) acc[e][mt] = (float4v){0.f, 0.f, 0.f, 0.f};

#pragma unroll
        for (int c = 0; c < CH; ++c) {
            half8 a[MT];
#pragma unroll
            for (int mt = 0; mt < MT; ++mt)
                a[mt] = (ZLAST && c == CH - 1)
                            ? *(const half8*)&zBase[mt * 16 * ZSTR]
                            : *(const half8*)&aBase[mt * 16 * sstr + c * 32];
            half8 b[EXPP];
#pragma unroll
            for (int e = 0; e < EXPP; ++e)
                b[e] = *(const half8*)&wbase[(size_t)(h * EXPP + e) * estr + c * 512];
#pragma unroll
            for (int e = 0; e < EXPP; ++e)
#pragma unroll
                for (int mt = 0; mt < MT; ++mt)
                    acc[e][mt] = __builtin_amdgcn_mfma_f32_16x16x32_f16(a[mt], b[e], acc[e][mt], 0, 0, 0);
        }

        // pass-h epilogue (all conditions constant-fold under full unroll)
#pragma unroll
        for (int mt = 0; mt < MT; ++mt)
#pragma unroll
            for (int r = 0; r < 4; ++r) {
                const int rl = mrow + mt * 16 + quad * 4 + r;
                float val;
                if constexpr (EXPP * NPASS == 1) {
                    val = acc[0][mt][r] + bv[0];
                } else {
                    const float2v cf = *(const float2v*)&sCf[rl * 8 + h * EXPP];  // EXPP==2
                    val = cf[0] * (acc[0][mt][r] + bv[0]);
                    val += cf[1] * (acc[1][mt][r] + bv[1]);
                }
                part[mt][r] = (h == 0) ? val : part[mt][r] + val;
                if (h == NPASS - 1) {
                    float o = part[mt][r];
                    if (DST == 0) {
                        if (ACT) o = elu_fast(o);
                        sDst[rl * ACTSTR + col] = (half_t)o;
                    } else {
                        gOut[(size_t)(row0 + rl) * ldg + col] = o;
                    }
                }
            }
    }
}

// Logits: N=8, wave 0 only. Wg3 in frag-block layout (NS=2, CH=8), strip 0.
__device__ __forceinline__ void layer_logits(
    const half_t* sSrc, const half_t* __restrict__ W,
    const float* __restrict__ bias, float* sLog, int wv, int lane, int l15, int quad) {
    if (wv != 0) return;
    float4v acc[2] = {(float4v){0.f, 0.f, 0.f, 0.f}, (float4v){0.f, 0.f, 0.f, 0.f}};
#pragma unroll
    for (int c = 0; c < 8; ++c) {
        half8 a0 = *(const half8*)&sSrc[l15 * ACTSTR + c * 32 + quad * 8];
        half8 a1 = *(const half8*)&sSrc[(16 + l15) * ACTSTR + c * 32 + quad * 8];
        half8 b = *(const half8*)&W[c * 512 + lane * 8];
        acc[0] = __builtin_amdgcn_mfma_f32_16x16x32_f16(a0, b, acc[0], 0, 0, 0);
        acc[1] = __builtin_amdgcn_mfma_f32_16x16x32_f16(a1, b, acc[1], 0, 0, 0);
    }
    if (l15 < 8) {
        const float bvv = bias[l15];
#pragma unroll
        for (int mt = 0; mt < 2; ++mt)
#pragma unroll
            for (int r = 0; r < 4; ++r)
                sLog[(mt * 16 + quad * 4 + r) * 8 + l15] = acc[mt][r] + bvv;
    }
}

__global__ __launch_bounds__(NT)
__attribute__((amdgpu_waves_per_eu(4, 4)))
void fused_mann(
    const float* __restrict__ x, const float* __restrict__ z,
    const half_t* __restrict__ Wg0, const half_t* __restrict__ Wg1,
    const half_t* __restrict__ Wg2, const half_t* __restrict__ Wg3,
    const float* __restrict__ gb0, const float* __restrict__ gb1,
    const float* __restrict__ gb2, const float* __restrict__ gb3,
    const half_t* __restrict__ W0, const half_t* __restrict__ W1,
    const half_t* __restrict__ W2, const float* __restrict__ b0,
    const float* __restrict__ b1, const float* __restrict__ b2,
    float* __restrict__ out) {
    extern __shared__ __align__(16) char dynsm[];
    half_t* sm = (half_t*)dynsm;
    half_t* sX = sm + OFF_SX;
    half_t* sB0 = sm + OFF_SB0;
    half_t* sB1 = sm + OFF_SB1;
    half_t* sZ = sm + OFF_SZ;
    float* sLog = (float*)(dynsm + OFF_LOG_B);
    float* sCf = (float*)(dynsm + OFF_CF_B);

    const int tid = threadIdx.x;
    const int row0 = blockIdx.x * 32;
    const int lane = tid & 63, wv = tid >> 6;  // 0..15
    const int l15 = lane & 15, quad = lane >> 4;

    for (int i = tid; i < 32 * 128; i += NT) {
        int r = i >> 7, c = i & 127;
        sX[r * XSTR + c] = (half_t)x[(size_t)(row0 + r) * 128 + c];
    }
    for (int i = tid; i < 32 * 32; i += NT) {
        int r = i >> 5, c = i & 31;
        sZ[r * ZSTR + c] = (half_t)z[(size_t)(row0 + r) * 32 + c];
    }
    __syncthreads();

    // Gating MLP (EXPP=1, 16 strips / 16 waves, MT=2)
    layer_run<1, 1, 5, 2, true, 1, 0>(sX, XSTR, sZ, Wg0, 16, gb0, 256, nullptr,
                                      sB0, nullptr, 0, row0, wv, 0, lane, l15, quad);
    __syncthreads();
    layer_run<1, 1, 8, 2, false, 1, 0>(sB0, ACTSTR, sZ, Wg1, 16, gb1, 256, nullptr,
                                       sB1, nullptr, 0, row0, wv, 0, lane, l15, quad);
    __syncthreads();
    layer_run<1, 1, 8, 2, false, 1, 0>(sB1, ACTSTR, sZ, Wg2, 16, gb2, 256, nullptr,
                                       sB0, nullptr, 0, row0, wv, 0, lane, l15, quad);
    __syncthreads();
    layer_logits(sB0, Wg3, gb3, sLog, wv, lane, l15, quad);
    __syncthreads();
    if (tid < 32) {
        float v[8], m = -1e30f;
#pragma unroll
        for (int e = 0; e < 8; ++e) { v[e] = sLog[tid * 8 + e]; m = fmaxf(m, v[e]); }
        float sum = 0.f;
#pragma unroll
        for (int e = 0; e < 8; ++e) { v[e] = __expf(v[e] - m); sum += v[e]; }
        float inv = 1.f / sum;
#pragma unroll
        for (int e = 0; e < 8; ++e) sCf[tid * 8 + e] = v[e] * inv;
    }
    __syncthreads();
    // Expert layers: 8 experts = 4 passes x 2
    layer_run<2, 4, 5, 2, true, 1, 0>(sX, XSTR, sZ, W0, 16, b0, 256, sCf,
                                      sB1, nullptr, 0, row0, wv, 0, lane, l15, quad);
    __syncthreads();
    layer_run<2, 4, 9, 2, true, 1, 0>(sB1, ACTSTR, sZ, W1, 16, b1, 256, sCf,
                                      sB0, nullptr, 0, row0, wv, 0, lane, l15, quad);
    __syncthreads();
    // Final: N=128 -> 8 strips x 2 m-halves over 16 waves (MT=1)
    layer_run<2, 4, 9, 1, true, 0, 2>(sB0, ACTSTR, sZ, W2, 8, b2, 128, sCf,
                                      nullptr, out, 128, row0, wv & 7, (wv >> 3) * 16,
                                      lane, l15, quad);
}

// Weight prep (validated r14): [E][K][N] fp32 -> frag-ordered fp16 1KB blocks
// dst[((e*NS + n/16)*CHN + k/32)*512 + ((k%32/8)*16 + n%16)*8 + k%8], zero-pad n>=N.
struct WDesc { const float* src; half_t* dst; int K, N, Npad, blk0; };
struct WPack { WDesc d[7]; };

__global__ __launch_bounds__(256) void conv_w_all(WPack pk) {
    __shared__ float t[32][33];
    const int bid = blockIdx.x;
    int di = 0;
#pragma unroll
    for (int i = 1; i < 7; ++i)
        if (bid >= pk.d[i].blk0) di = i;
    const WDesc d = pk.d[di];
    const int NS = d.Npad >> 4, CHN = d.K >> 5;
    const int ntiles = d.Npad / 32, ktiles = CHN;
    int local = bid - d.blk0;
    const int e = local / (ktiles * ntiles);
    local %= ktiles * ntiles;
    const int k0 = (local / ntiles) * 32, n0 = (local % ntiles) * 32;
    const int tr = threadIdx.x >> 3;        // 0..31
    const int tc = (threadIdx.x & 7) * 4;   // 0,4,..,28

    float4 v = {0.f, 0.f, 0.f, 0.f};
    if (n0 + tc < d.N)
        v = *(const float4*)&d.src[((size_t)e * d.K + k0 + tr) * d.N + n0 + tc];
    t[tr][tc] = v.x; t[tr][tc + 1] = v.y; t[tr][tc + 2] = v.z; t[tr][tc + 3] = v.w;
    __syncthreads();
    half4 h;
#pragma unroll
    for (int i = 0; i < 4; ++i) h[i] = (half_t)t[tc + i][tr];
    const int n = n0 + tr;
    const size_t blk = ((size_t)e * NS + (n >> 4)) * CHN + (k0 >> 5);
    const int off = ((tc >> 3) * 16 + (n & 15)) * 8 + (tc & 7);
    *(half4*)&d.dst[blk * 512 + off] = h;
}

extern "C" void kernel_launch(void* const* d_in, const int* in_sizes, int n_in,
                              void* d_out, int out_size, void* d_ws, size_t ws_size,
                              hipStream_t stream) {
    const float* x   = (const float*)d_in[0];
    const float* z   = (const float*)d_in[1];
    const float* gw0 = (const float*)d_in[2];
    const float* gb0 = (const float*)d_in[3];
    const float* gw1 = (const float*)d_in[4];
    const float* gb1 = (const float*)d_in[5];
    const float* gw2 = (const float*)d_in[6];
    const float* gb2 = (const float*)d_in[7];
    const float* gw3 = (const float*)d_in[8];
    const float* gb3 = (const float*)d_in[9];
    const float* w0  = (const float*)d_in[10];
    const float* b0  = (const float*)d_in[11];
    const float* w1  = (const float*)d_in[12];
    const float* b1  = (const float*)d_in[13];
    const float* w2  = (const float*)d_in[14];
    const float* b2  = (const float*)d_in[15];

    char* p = (char*)d_ws;
    auto take = [&](size_t bytes) { char* r = p; p += bytes; return r; };
    half_t* Wg0 = (half_t*)take((size_t)256 * 160 * 2);
    half_t* Wg1 = (half_t*)take((size_t)256 * 256 * 2);
    half_t* Wg2 = (half_t*)take((size_t)256 * 256 * 2);
    half_t* Wg3 = (half_t*)take((size_t)32 * 256 * 2);
    half_t* W0  = (half_t*)take((size_t)8 * 256 * 160 * 2);
    half_t* W1  = (half_t*)take((size_t)8 * 256 * 288 * 2);
    half_t* W2  = (half_t*)take((size_t)8 * 128 * 288 * 2);
    float* out  = (float*)d_out;

    WPack pk;
    int blk = 0;
    auto mk = [&](int i, const float* s, half_t* dst, int K, int N, int Npad, int E) {
        pk.d[i] = WDesc{s, dst, K, N, Npad, blk};
        blk += E * (K / 32) * (Npad / 32);
    };
    mk(0, gw0, Wg0, 160, 256, 256, 1);
    mk(1, gw1, Wg1, 256, 256, 256, 1);
    mk(2, gw2, Wg2, 256, 256, 256, 1);
    mk(3, gw3, Wg3, 256, 8, 32, 1);
    mk(4, w0, W0, 160, 256, 256, 8);
    mk(5, w1, W1, 288, 256, 256, 8);
    mk(6, w2, W2, 288, 128, 128, 8);

    hipFuncSetAttribute((const void*)fused_mann,
                        hipFuncAttributeMaxDynamicSharedMemorySize, SMEM_BYTES);

    conv_w_all<<<dim3(blk), dim3(256), 0, stream>>>(pk);
    fused_mann<<<dim3(BSZ / 32), dim3(NT), SMEM_BYTES, stream>>>(
        x, z, Wg0, Wg1, Wg2, Wg3, gb0, gb1, gb2, gb3,
        W0, W1, W2, b0, b1, b2, out);
}

// Round 4
// 145.645 us; speedup vs baseline: 1.0024x; 1.0024x over previous
//
#include <hip/hip_runtime.h>
#include <hip/hip_bf16.h>

typedef _Float16 half_t;
typedef __attribute__((ext_vector_type(8))) _Float16 half8;
typedef __attribute__((ext_vector_type(4))) _Float16 half4;
typedef __attribute__((ext_vector_type(4))) float float4v;
typedef __attribute__((ext_vector_type(2))) float float2v;

#define BSZ 8192
#define NT 1024   // 16 waves, grid 256 = 1 block/CU
#define ACTSTR 280  // act stride (halfs): 560B, 16B-aligned
#define XSTR 152    // x stride: 304B
#define ZSTR 40     // z stride: 80B

// ---- dynamic LDS layout (half_t units unless noted) ----
// B-weight ring REMOVED (r1): weights stream HBM/L2 -> VGPR directly — B has
// zero reuse, so LDS staging was pure FIFO overhead on the LDS pipe.
#define OFF_SX 0
#define OFF_SB0 (OFF_SX + 32 * XSTR)
#define OFF_SB1 (OFF_SB0 + 32 * ACTSTR)
#define OFF_SZ (OFF_SB1 + 32 * ACTSTR)
#define HALFS_TOTAL (OFF_SZ + 32 * ZSTR)   // 24064 halfs = 48128 B
#define OFF_LOG_B (HALFS_TOTAL * 2)
#define OFF_CF_B (OFF_LOG_B + 1024)
#define SMEM_BYTES (OFF_CF_B + 1024)       // 50176 B

__device__ __forceinline__ float elu_fast(float v) {
    return v > 0.f ? v : (__expf(v) - 1.f);
}

// W layout (validated r14): frag-ordered 1KB blocks [e][strip][chunk][512 halfs],
// block[(quad*16+l15)*8+j] = W[n=strip*16+l15][k=chunk*32+quad*8+j]. A lane's
// B fragment is 16B at base + lane*16B -> one coalesced global_load_dwordx4.
//
// r1-r3 LESSON (spill saga): fully unrolling the NPASS*CH loop let the pre-RA
// scheduler hoist up to 72 B-loads -> ~30-40MB/dispatch of scratch (WRITE_SIZE
// 4->32->40MB), VGPR pinned at 64 by the backend's occupancy heuristic, which
// NEITHER __launch_bounds__(NT,4) NOR amdgpu_waves_per_eu(4,4) overrides.
// Fix the PRESSURE, not the budget: flattened `#pragma unroll 1` (pass,chunk)
// loop with explicit depth-1 register prefetch (consume bc[], load bn[],
// rotate). Live set ~60 VGPRs -> fits the 64 budget, no spill.
template <int EXPP, int NPASS, int CH, int MT, bool ZLAST, int ACT, int DST>
__device__ __forceinline__ void layer_run(
    const half_t* sSrc, int sstr, const half_t* sZ,
    const half_t* __restrict__ W, int NS,
    const float* __restrict__ bias, int biasN, const float* sCf,
    half_t* sDst, float* __restrict__ gOut, int ldg,
    int row0, int strip, int mrow, int lane, int l15, int quad) {
    constexpr int TOT = NPASS * CH;
    const size_t estr = (size_t)NS * CH * 512;  // halfs per expert in layout
    const int col = strip * 16 + l15;
    const half_t* aBase = sSrc + (mrow + l15) * sstr + quad * 8;
    const half_t* zBase = sZ + (mrow + l15) * ZSTR + quad * 8;

    // issue pointer: address of body-i's B fragments (advances chunk-by-chunk)
    const half_t* wp = W + (size_t)strip * CH * 512 + lane * 8;
    int c_i = 0;
    half8 bc[EXPP], bn[EXPP];
#pragma unroll
    for (int e = 0; e < EXPP; ++e) bc[e] = *(const half8*)&wp[(size_t)e * estr];
    wp += 512;
    if (++c_i == CH) { c_i = 0; wp += EXPP * estr - (size_t)CH * 512; }

    const float* bp = bias + col;
    float part[MT][4];
    float bv[EXPP];
    float4v acc[EXPP][MT];

    int c_c = 0, h_c = 0;
#pragma unroll 1
    for (int it = 0; it < TOT; ++it) {
        // prefetch body it+1's B fragments (depth-1 pipeline, never stalls MFMA)
        if (it + 1 < TOT) {
#pragma unroll
            for (int e = 0; e < EXPP; ++e) bn[e] = *(const half8*)&wp[(size_t)e * estr];
            wp += 512;
            if (++c_i == CH) { c_i = 0; wp += EXPP * estr - (size_t)CH * 512; }
        }
        if (c_c == 0) {
#pragma unroll
            for (int e = 0; e < EXPP; ++e) bv[e] = bp[(size_t)e * biasN];
#pragma unroll
            for (int e = 0; e < EXPP; ++e)
#pragma unroll
                for (int mt = 0; mt < MT; ++mt) acc[e][mt] = (float4v){0.f, 0.f, 0.f, 0.f};
        }
        half8 a[MT];
#pragma unroll
        for (int mt = 0; mt < MT; ++mt)
            a[mt] = (ZLAST && c_c == CH - 1)
                        ? *(const half8*)&zBase[mt * 16 * ZSTR]
                        : *(const half8*)&aBase[mt * 16 * sstr + c_c * 32];
#pragma unroll
        for (int e = 0; e < EXPP; ++e)
#pragma unroll
            for (int mt = 0; mt < MT; ++mt)
                acc[e][mt] = __builtin_amdgcn_mfma_f32_16x16x32_f16(a[mt], bc[e], acc[e][mt], 0, 0, 0);

        if (c_c == CH - 1) {  // pass-h_c epilogue
#pragma unroll
            for (int mt = 0; mt < MT; ++mt)
#pragma unroll
                for (int r = 0; r < 4; ++r) {
                    const int rl = mrow + mt * 16 + quad * 4 + r;
                    float val;
                    if constexpr (EXPP * NPASS == 1) {
                        val = acc[0][mt][r] + bv[0];
                    } else {
                        const float2v cf = *(const float2v*)&sCf[rl * 8 + h_c * EXPP];  // EXPP==2
                        val = cf[0] * (acc[0][mt][r] + bv[0]);
                        val += cf[1] * (acc[1][mt][r] + bv[1]);
                    }
                    part[mt][r] = (h_c == 0) ? val : part[mt][r] + val;
                    if (h_c == NPASS - 1) {
                        float o = part[mt][r];
                        if (DST == 0) {
                            if (ACT) o = elu_fast(o);
                            sDst[rl * ACTSTR + col] = (half_t)o;
                        } else {
                            gOut[(size_t)(row0 + rl) * ldg + col] = o;
                        }
                    }
                }
            bp += (size_t)EXPP * biasN;
        }
        // rotate prefetch registers (static indices only — no scratch)
#pragma unroll
        for (int e = 0; e < EXPP; ++e) bc[e] = bn[e];
        if (++c_c == CH) { c_c = 0; ++h_c; }
    }
}

// Logits: N=8, wave 0 only. Wg3 in frag-block layout (NS=2, CH=8), strip 0.
__device__ __forceinline__ void layer_logits(
    const half_t* sSrc, const half_t* __restrict__ W,
    const float* __restrict__ bias, float* sLog, int wv, int lane, int l15, int quad) {
    if (wv != 0) return;
    float4v acc[2] = {(float4v){0.f, 0.f, 0.f, 0.f}, (float4v){0.f, 0.f, 0.f, 0.f}};
#pragma unroll
    for (int c = 0; c < 8; ++c) {
        half8 a0 = *(const half8*)&sSrc[l15 * ACTSTR + c * 32 + quad * 8];
        half8 a1 = *(const half8*)&sSrc[(16 + l15) * ACTSTR + c * 32 + quad * 8];
        half8 b = *(const half8*)&W[c * 512 + lane * 8];
        acc[0] = __builtin_amdgcn_mfma_f32_16x16x32_f16(a0, b, acc[0], 0, 0, 0);
        acc[1] = __builtin_amdgcn_mfma_f32_16x16x32_f16(a1, b, acc[1], 0, 0, 0);
    }
    if (l15 < 8) {
        const float bvv = bias[l15];
#pragma unroll
        for (int mt = 0; mt < 2; ++mt)
#pragma unroll
            for (int r = 0; r < 4; ++r)
                sLog[(mt * 16 + quad * 4 + r) * 8 + l15] = acc[mt][r] + bvv;
    }
}

__global__ __launch_bounds__(NT) void fused_mann(
    const float* __restrict__ x, const float* __restrict__ z,
    const half_t* __restrict__ Wg0, const half_t* __restrict__ Wg1,
    const half_t* __restrict__ Wg2, const half_t* __restrict__ Wg3,
    const float* __restrict__ gb0, const float* __restrict__ gb1,
    const float* __restrict__ gb2, const float* __restrict__ gb3,
    const half_t* __restrict__ W0, const half_t* __restrict__ W1,
    const half_t* __restrict__ W2, const float* __restrict__ b0,
    const float* __restrict__ b1, const float* __restrict__ b2,
    float* __restrict__ out) {
    extern __shared__ __align__(16) char dynsm[];
    half_t* sm = (half_t*)dynsm;
    half_t* sX = sm + OFF_SX;
    half_t* sB0 = sm + OFF_SB0;
    half_t* sB1 = sm + OFF_SB1;
    half_t* sZ = sm + OFF_SZ;
    float* sLog = (float*)(dynsm + OFF_LOG_B);
    float* sCf = (float*)(dynsm + OFF_CF_B);

    const int tid = threadIdx.x;
    const int row0 = blockIdx.x * 32;
    const int lane = tid & 63, wv = tid >> 6;  // 0..15
    const int l15 = lane & 15, quad = lane >> 4;

    for (int i = tid; i < 32 * 128; i += NT) {
        int r = i >> 7, c = i & 127;
        sX[r * XSTR + c] = (half_t)x[(size_t)(row0 + r) * 128 + c];
    }
    for (int i = tid; i < 32 * 32; i += NT) {
        int r = i >> 5, c = i & 31;
        sZ[r * ZSTR + c] = (half_t)z[(size_t)(row0 + r) * 32 + c];
    }
    __syncthreads();

    // Gating MLP (EXPP=1, 16 strips / 16 waves, MT=2)
    layer_run<1, 1, 5, 2, true, 1, 0>(sX, XSTR, sZ, Wg0, 16, gb0, 256, nullptr,
                                      sB0, nullptr, 0, row0, wv, 0, lane, l15, quad);
    __syncthreads();
    layer_run<1, 1, 8, 2, false, 1, 0>(sB0, ACTSTR, sZ, Wg1, 16, gb1, 256, nullptr,
                                       sB1, nullptr, 0, row0, wv, 0, lane, l15, quad);
    __syncthreads();
    layer_run<1, 1, 8, 2, false, 1, 0>(sB1, ACTSTR, sZ, Wg2, 16, gb2, 256, nullptr,
                                       sB0, nullptr, 0, row0, wv, 0, lane, l15, quad);
    __syncthreads();
    layer_logits(sB0, Wg3, gb3, sLog, wv, lane, l15, quad);
    __syncthreads();
    if (tid < 32) {
        float v[8], m = -1e30f;
#pragma unroll
        for (int e = 0; e < 8; ++e) { v[e] = sLog[tid * 8 + e]; m = fmaxf(m, v[e]); }
        float sum = 0.f;
#pragma unroll
        for (int e = 0; e < 8; ++e) { v[e] = __expf(v[e] - m); sum += v[e]; }
        float inv = 1.f / sum;
#pragma unroll
        for (int e = 0; e < 8; ++e) sCf[tid * 8 + e] = v[e] * inv;
    }
    __syncthreads();
    // Expert layers: 8 experts = 4 passes x 2
    layer_run<2, 4, 5, 2, true, 1, 0>(sX, XSTR, sZ, W0, 16, b0, 256, sCf,
                                      sB1, nullptr, 0, row0, wv, 0, lane, l15, quad);
    __syncthreads();
    layer_run<2, 4, 9, 2, true, 1, 0>(sB1, ACTSTR, sZ, W1, 16, b1, 256, sCf,
                                      sB0, nullptr, 0, row0, wv, 0, lane, l15, quad);
    __syncthreads();
    // Final: N=128 -> 8 strips x 2 m-halves over 16 waves (MT=1)
    layer_run<2, 4, 9, 1, true, 0, 2>(sB0, ACTSTR, sZ, W2, 8, b2, 128, sCf,
                                      nullptr, out, 128, row0, wv & 7, (wv >> 3) * 16,
                                      lane, l15, quad);
}

// Weight prep (validated r14): [E][K][N] fp32 -> frag-ordered fp16 1KB blocks
// dst[((e*NS + n/16)*CHN + k/32)*512 + ((k%32/8)*16 + n%16)*8 + k%8], zero-pad n>=N.
struct WDesc { const float* src; half_t* dst; int K, N, Npad, blk0; };
struct WPack { WDesc d[7]; };

__global__ __launch_bounds__(256) void conv_w_all(WPack pk) {
    __shared__ float t[32][33];
    const int bid = blockIdx.x;
    int di = 0;
#pragma unroll
    for (int i = 1; i < 7; ++i)
        if (bid >= pk.d[i].blk0) di = i;
    const WDesc d = pk.d[di];
    const int NS = d.Npad >> 4, CHN = d.K >> 5;
    const int ntiles = d.Npad / 32, ktiles = CHN;
    int local = bid - d.blk0;
    const int e = local / (ktiles * ntiles);
    local %= ktiles * ntiles;
    const int k0 = (local / ntiles) * 32, n0 = (local % ntiles) * 32;
    const int tr = threadIdx.x >> 3;        // 0..31
    const int tc = (threadIdx.x & 7) * 4;   // 0,4,..,28

    float4 v = {0.f, 0.f, 0.f, 0.f};
    if (n0 + tc < d.N)
        v = *(const float4*)&d.src[((size_t)e * d.K + k0 + tr) * d.N + n0 + tc];
    t[tr][tc] = v.x; t[tr][tc + 1] = v.y; t[tr][tc + 2] = v.z; t[tr][tc + 3] = v.w;
    __syncthreads();
    half4 h;
#pragma unroll
    for (int i = 0; i < 4; ++i) h[i] = (half_t)t[tc + i][tr];
    const int n = n0 + tr;
    const size_t blk = ((size_t)e * NS + (n >> 4)) * CHN + (k0 >> 5);
    const int off = ((tc >> 3) * 16 + (n & 15)) * 8 + (tc & 7);
    *(half4*)&d.dst[blk * 512 + off] = h;
}

extern "C" void kernel_launch(void* const* d_in, const int* in_sizes, int n_in,
                              void* d_out, int out_size, void* d_ws, size_t ws_size,
                              hipStream_t stream) {
    const float* x   = (const float*)d_in[0];
    const float* z   = (const float*)d_in[1];
    const float* gw0 = (const float*)d_in[2];
    const float* gb0 = (const float*)d_in[3];
    const float* gw1 = (const float*)d_in[4];
    const float* gb1 = (const float*)d_in[5];
    const float* gw2 = (const float*)d_in[6];
    const float* gb2 = (const float*)d_in[7];
    const float* gw3 = (const float*)d_in[8];
    const float* gb3 = (const float*)d_in[9];
    const float* w0  = (const float*)d_in[10];
    const float* b0  = (const float*)d_in[11];
    const float* w1  = (const float*)d_in[12];
    const float* b1  = (const float*)d_in[13];
    const float* w2  = (const float*)d_in[14];
    const float* b2  = (const float*)d_in[15];

    char* p = (char*)d_ws;
    auto take = [&](size_t bytes) { char* r = p; p += bytes; return r; };
    half_t* Wg0 = (half_t*)take((size_t)256 * 160 * 2);
    half_t* Wg1 = (half_t*)take((size_t)256 * 256 * 2);
    half_t* Wg2 = (half_t*)take((size_t)256 * 256 * 2);
    half_t* Wg3 = (half_t*)take((size_t)32 * 256 * 2);
    half_t* W0  = (half_t*)take((size_t)8 * 256 * 160 * 2);
    half_t* W1  = (half_t*)take((size_t)8 * 256 * 288 * 2);
    half_t* W2  = (half_t*)take((size_t)8 * 128 * 288 * 2);
    float* out  = (float*)d_out;

    WPack pk;
    int blk = 0;
    auto mk = [&](int i, const float* s, half_t* dst, int K, int N, int Npad, int E) {
        pk.d[i] = WDesc{s, dst, K, N, Npad, blk};
        blk += E * (K / 32) * (Npad / 32);
    };
    mk(0, gw0, Wg0, 160, 256, 256, 1);
    mk(1, gw1, Wg1, 256, 256, 256, 1);
    mk(2, gw2, Wg2, 256, 256, 256, 1);
    mk(3, gw3, Wg3, 256, 8, 32, 1);
    mk(4, w0, W0, 160, 256, 256, 8);
    mk(5, w1, W1, 288, 256, 256, 8);
    mk(6, w2, W2, 288, 128, 128, 8);

    hipFuncSetAttribute((const void*)fused_mann,
                        hipFuncAttributeMaxDynamicSharedMemorySize, SMEM_BYTES);

    conv_w_all<<<dim3(blk), dim3(256), 0, stream>>>(pk);
    fused_mann<<<dim3(BSZ / 32), dim3(NT), SMEM_BYTES, stream>>>(
        x, z, Wg0, Wg1, Wg2, Wg3, gb0, gb1, gb2, gb3,
        W0, W1, W2, b0, b1, b2, out);
}

// Round 5
// 131.326 us; speedup vs baseline: 1.1116x; 1.1090x over previous
//
#include <hip/hip_runtime.h>
#include <hip/hip_bf16.h>

typedef _Float16 half_t;
typedef __attribute__((ext_vector_type(8))) _Float16 half8;
typedef __attribute__((ext_vector_type(4))) _Float16 half4;
typedef __attribute__((ext_vector_type(4))) float float4v;
typedef __attribute__((ext_vector_type(2))) float float2v;

#define BSZ 8192
#define NT 1024   // 16 waves, grid 256 = 1 block/CU
#define ACTSTR 280  // act stride (halfs): 560B, 16B-aligned
#define XSTR 152    // x stride: 304B
#define ZSTR 40     // z stride: 80B

// ---- dynamic LDS layout (half_t units unless noted) ----
#define OFF_SX 0
#define OFF_SB0 (OFF_SX + 32 * XSTR)
#define OFF_SB1 (OFF_SB0 + 32 * ACTSTR)
#define OFF_SZ (OFF_SB1 + 32 * ACTSTR)
#define HALFS_TOTAL (OFF_SZ + 32 * ZSTR)   // 24064 halfs = 48128 B
#define OFF_LOG_B (HALFS_TOTAL * 2)
#define OFF_CF_B (OFF_LOG_B + 1024)
// r4 LESSON: the backend budgets VGPRs from the LDS-derived occupancy bound.
// At 50KB it budgeted for 2-3 blocks/CU (42-64 VGPRs) even though the grid is
// 1 block/CU by construction — and neither __launch_bounds__(NT,4) nor
// amdgpu_waves_per_eu(4,4) overrode it (r2/r3). PAD dynamic LDS past 80KB so
// the bound itself says 1 block/CU -> 4 waves/SIMD -> 128-VGPR budget.
#define SMEM_BYTES 131072

__device__ __forceinline__ float elu_fast(float v) {
    return v > 0.f ? v : (__expf(v) - 1.f);
}

// W layout (validated r14): frag-ordered 1KB blocks [e][strip][chunk][512 halfs],
// block[(quad*16+l15)*8+j] = W[n=strip*16+l15][k=chunk*32+quad*8+j]. A lane's
// B fragment is 16B at base + lane*16B -> one coalesced global_load_dwordx4.
//
// r4 LESSON (latency, not bandwidth): A ds_reads were issued in the SAME body
// that consumed them (zero lgkmcnt slack; queued LDS latency ~300cy with 16
// waves loading the pipe) and the B rotation movs forced vmcnt(0) at ~1-body
// slack. MfmaUtil+VALUBusy < 50% with every pipe's BW far from saturated =
// correlated all-wave stalls. Fix: unroll-2 ping-pong software pipeline —
// even bodies consume (B0,A0), odd consume (B1,A1), each issued one body
// ahead; no rotation movs, all register indices static.
template <int EXPP, int NPASS, int CH, int MT, bool ZLAST, int ACT, int DST>
__device__ __forceinline__ void layer_run(
    const half_t* sSrc, int sstr, const half_t* sZ,
    const half_t* __restrict__ W, int NS,
    const float* __restrict__ bias, int biasN, const float* sCf,
    half_t* sDst, float* __restrict__ gOut, int ldg,
    int row0, int strip, int mrow, int lane, int l15, int quad) {
    constexpr int TOT = NPASS * CH;
    const size_t estr = (size_t)NS * CH * 512;  // halfs per expert in layout
    const int col = strip * 16 + l15;
    const half_t* aBase = sSrc + (mrow + l15) * sstr + quad * 8;
    const half_t* zBase = sZ + (mrow + l15) * ZSTR + quad * 8;

    // issue-side state (walks chunk-by-chunk through the frag-ordered layout)
    const half_t* wp = W + (size_t)strip * CH * 512 + lane * 8;
    int c_i = 0;
    // compute-side state
    const float* bp = bias + col;
    int c_c = 0, h_c = 0;

    half8 B0[EXPP], B1[EXPP], A0[MT], A1[MT];
    float part[MT][4];
    float bv[EXPP];
    float4v acc[EXPP][MT];

    auto issue = [&](half8(&B)[EXPP], half8(&A)[MT]) {
#pragma unroll
        for (int e = 0; e < EXPP; ++e) B[e] = *(const half8*)&wp[(size_t)e * estr];
#pragma unroll
        for (int mt = 0; mt < MT; ++mt)
            A[mt] = (ZLAST && c_i == CH - 1)
                        ? *(const half8*)&zBase[mt * 16 * ZSTR]
                        : *(const half8*)&aBase[mt * 16 * sstr + c_i * 32];
        wp += 512;
        if (++c_i == CH) { c_i = 0; wp += (size_t)EXPP * estr - (size_t)CH * 512; }
    };

    auto body = [&](half8(&B)[EXPP], half8(&A)[MT]) {
        if (c_c == 0) {
#pragma unroll
            for (int e = 0; e < EXPP; ++e) bv[e] = bp[(size_t)e * biasN];
#pragma unroll
            for (int e = 0; e < EXPP; ++e)
#pragma unroll
                for (int mt = 0; mt < MT; ++mt) acc[e][mt] = (float4v){0.f, 0.f, 0.f, 0.f};
        }
#pragma unroll
        for (int e = 0; e < EXPP; ++e)
#pragma unroll
            for (int mt = 0; mt < MT; ++mt)
                acc[e][mt] = __builtin_amdgcn_mfma_f32_16x16x32_f16(A[mt], B[e], acc[e][mt], 0, 0, 0);
        if (c_c == CH - 1) {  // pass-h_c epilogue
#pragma unroll
            for (int mt = 0; mt < MT; ++mt)
#pragma unroll
                for (int r = 0; r < 4; ++r) {
                    const int rl = mrow + mt * 16 + quad * 4 + r;
                    float val;
                    if constexpr (EXPP * NPASS == 1) {
                        val = acc[0][mt][r] + bv[0];
                    } else {
                        const float2v cf = *(const float2v*)&sCf[rl * 8 + h_c * EXPP];  // EXPP==2
                        val = cf[0] * (acc[0][mt][r] + bv[0]);
                        val += cf[1] * (acc[1][mt][r] + bv[1]);
                    }
                    part[mt][r] = (h_c == 0) ? val : part[mt][r] + val;
                    if (h_c == NPASS - 1) {
                        float o = part[mt][r];
                        if (DST == 0) {
                            if (ACT) o = elu_fast(o);
                            sDst[rl * ACTSTR + col] = (half_t)o;
                        } else {
                            gOut[(size_t)(row0 + rl) * ldg + col] = o;
                        }
                    }
                }
            bp += (size_t)EXPP * biasN;
        }
        if (++c_c == CH) { c_c = 0; ++h_c; }
    };

    issue(B0, A0);  // body 0
    int it = 0;
#pragma unroll 1
    for (; it + 2 < TOT; it += 2) {
        issue(B1, A1);  // body it+1 (1-body slack before body(B1,A1))
        body(B0, A0);   // body it   (its frags issued 1 body ago)
        issue(B0, A0);  // body it+2 (safe: it+2 < TOT)
        body(B1, A1);   // body it+1
    }
    if constexpr (TOT % 2 == 0) {  // remainder 2
        issue(B1, A1);
        body(B0, A0);
        body(B1, A1);
    } else {  // remainder 1
        body(B0, A0);
    }
}

// Logits: N=8, wave 0 only. Wg3 in frag-block layout (NS=2, CH=8), strip 0.
__device__ __forceinline__ void layer_logits(
    const half_t* sSrc, const half_t* __restrict__ W,
    const float* __restrict__ bias, float* sLog, int wv, int lane, int l15, int quad) {
    if (wv != 0) return;
    float4v acc[2] = {(float4v){0.f, 0.f, 0.f, 0.f}, (float4v){0.f, 0.f, 0.f, 0.f}};
#pragma unroll
    for (int c = 0; c < 8; ++c) {
        half8 a0 = *(const half8*)&sSrc[l15 * ACTSTR + c * 32 + quad * 8];
        half8 a1 = *(const half8*)&sSrc[(16 + l15) * ACTSTR + c * 32 + quad * 8];
        half8 b = *(const half8*)&W[c * 512 + lane * 8];
        acc[0] = __builtin_amdgcn_mfma_f32_16x16x32_f16(a0, b, acc[0], 0, 0, 0);
        acc[1] = __builtin_amdgcn_mfma_f32_16x16x32_f16(a1, b, acc[1], 0, 0, 0);
    }
    if (l15 < 8) {
        const float bvv = bias[l15];
#pragma unroll
        for (int mt = 0; mt < 2; ++mt)
#pragma unroll
            for (int r = 0; r < 4; ++r)
                sLog[(mt * 16 + quad * 4 + r) * 8 + l15] = acc[mt][r] + bvv;
    }
}

__global__ __launch_bounds__(NT) void fused_mann(
    const float* __restrict__ x, const float* __restrict__ z,
    const half_t* __restrict__ Wg0, const half_t* __restrict__ Wg1,
    const half_t* __restrict__ Wg2, const half_t* __restrict__ Wg3,
    const float* __restrict__ gb0, const float* __restrict__ gb1,
    const float* __restrict__ gb2, const float* __restrict__ gb3,
    const half_t* __restrict__ W0, const half_t* __restrict__ W1,
    const half_t* __restrict__ W2, const float* __restrict__ b0,
    const float* __restrict__ b1, const float* __restrict__ b2,
    float* __restrict__ out) {
    extern __shared__ __align__(16) char dynsm[];
    half_t* sm = (half_t*)dynsm;
    half_t* sX = sm + OFF_SX;
    half_t* sB0 = sm + OFF_SB0;
    half_t* sB1 = sm + OFF_SB1;
    half_t* sZ = sm + OFF_SZ;
    float* sLog = (float*)(dynsm + OFF_LOG_B);
    float* sCf = (float*)(dynsm + OFF_CF_B);

    const int tid = threadIdx.x;
    const int row0 = blockIdx.x * 32;
    const int lane = tid & 63, wv = tid >> 6;  // 0..15
    const int l15 = lane & 15, quad = lane >> 4;

    for (int i = tid; i < 32 * 128; i += NT) {
        int r = i >> 7, c = i & 127;
        sX[r * XSTR + c] = (half_t)x[(size_t)(row0 + r) * 128 + c];
    }
    for (int i = tid; i < 32 * 32; i += NT) {
        int r = i >> 5, c = i & 31;
        sZ[r * ZSTR + c] = (half_t)z[(size_t)(row0 + r) * 32 + c];
    }
    __syncthreads();

    // Gating MLP (EXPP=1, 16 strips / 16 waves, MT=2)
    layer_run<1, 1, 5, 2, true, 1, 0>(sX, XSTR, sZ, Wg0, 16, gb0, 256, nullptr,
                                      sB0, nullptr, 0, row0, wv, 0, lane, l15, quad);
    __syncthreads();
    layer_run<1, 1, 8, 2, false, 1, 0>(sB0, ACTSTR, sZ, Wg1, 16, gb1, 256, nullptr,
                                       sB1, nullptr, 0, row0, wv, 0, lane, l15, quad);
    __syncthreads();
    layer_run<1, 1, 8, 2, false, 1, 0>(sB1, ACTSTR, sZ, Wg2, 16, gb2, 256, nullptr,
                                       sB0, nullptr, 0, row0, wv, 0, lane, l15, quad);
    __syncthreads();
    layer_logits(sB0, Wg3, gb3, sLog, wv, lane, l15, quad);
    __syncthreads();
    if (tid < 32) {
        float v[8], m = -1e30f;
#pragma unroll
        for (int e = 0; e < 8; ++e) { v[e] = sLog[tid * 8 + e]; m = fmaxf(m, v[e]); }
        float sum = 0.f;
#pragma unroll
        for (int e = 0; e < 8; ++e) { v[e] = __expf(v[e] - m); sum += v[e]; }
        float inv = 1.f / sum;
#pragma unroll
        for (int e = 0; e < 8; ++e) sCf[tid * 8 + e] = v[e] * inv;
    }
    __syncthreads();
    // Expert layers: 8 experts = 4 passes x 2
    layer_run<2, 4, 5, 2, true, 1, 0>(sX, XSTR, sZ, W0, 16, b0, 256, sCf,
                                      sB1, nullptr, 0, row0, wv, 0, lane, l15, quad);
    __syncthreads();
    layer_run<2, 4, 9, 2, true, 1, 0>(sB1, ACTSTR, sZ, W1, 16, b1, 256, sCf,
                                      sB0, nullptr, 0, row0, wv, 0, lane, l15, quad);
    __syncthreads();
    // Final: N=128 -> 8 strips x 2 m-halves over 16 waves (MT=1)
    layer_run<2, 4, 9, 1, true, 0, 2>(sB0, ACTSTR, sZ, W2, 8, b2, 128, sCf,
                                      nullptr, out, 128, row0, wv & 7, (wv >> 3) * 16,
                                      lane, l15, quad);
}

// Weight prep (validated r14): [E][K][N] fp32 -> frag-ordered fp16 1KB blocks
// dst[((e*NS + n/16)*CHN + k/32)*512 + ((k%32/8)*16 + n%16)*8 + k%8], zero-pad n>=N.
struct WDesc { const float* src; half_t* dst; int K, N, Npad, blk0; };
struct WPack { WDesc d[7]; };

__global__ __launch_bounds__(256) void conv_w_all(WPack pk) {
    __shared__ float t[32][33];
    const int bid = blockIdx.x;
    int di = 0;
#pragma unroll
    for (int i = 1; i < 7; ++i)
        if (bid >= pk.d[i].blk0) di = i;
    const WDesc d = pk.d[di];
    const int NS = d.Npad >> 4, CHN = d.K >> 5;
    const int ntiles = d.Npad / 32, ktiles = CHN;
    int local = bid - d.blk0;
    const int e = local / (ktiles * ntiles);
    local %= ktiles * ntiles;
    const int k0 = (local / ntiles) * 32, n0 = (local % ntiles) * 32;
    const int tr = threadIdx.x >> 3;        // 0..31
    const int tc = (threadIdx.x & 7) * 4;   // 0,4,..,28

    float4 v = {0.f, 0.f, 0.f, 0.f};
    if (n0 + tc < d.N)
        v = *(const float4*)&d.src[((size_t)e * d.K + k0 + tr) * d.N + n0 + tc];
    t[tr][tc] = v.x; t[tr][tc + 1] = v.y; t[tr][tc + 2] = v.z; t[tr][tc + 3] = v.w;
    __syncthreads();
    half4 h;
#pragma unroll
    for (int i = 0; i < 4; ++i) h[i] = (half_t)t[tc + i][tr];
    const int n = n0 + tr;
    const size_t blk = ((size_t)e * NS + (n >> 4)) * CHN + (k0 >> 5);
    const int off = ((tc >> 3) * 16 + (n & 15)) * 8 + (tc & 7);
    *(half4*)&d.dst[blk * 512 + off] = h;
}

extern "C" void kernel_launch(void* const* d_in, const int* in_sizes, int n_in,
                              void* d_out, int out_size, void* d_ws, size_t ws_size,
                              hipStream_t stream) {
    const float* x   = (const float*)d_in[0];
    const float* z   = (const float*)d_in[1];
    const float* gw0 = (const float*)d_in[2];
    const float* gb0 = (const float*)d_in[3];
    const float* gw1 = (const float*)d_in[4];
    const float* gb1 = (const float*)d_in[5];
    const float* gw2 = (const float*)d_in[6];
    const float* gb2 = (const float*)d_in[7];
    const float* gw3 = (const float*)d_in[8];
    const float* gb3 = (const float*)d_in[9];
    const float* w0  = (const float*)d_in[10];
    const float* b0  = (const float*)d_in[11];
    const float* w1  = (const float*)d_in[12];
    const float* b1  = (const float*)d_in[13];
    const float* w2  = (const float*)d_in[14];
    const float* b2  = (const float*)d_in[15];

    char* p = (char*)d_ws;
    auto take = [&](size_t bytes) { char* r = p; p += bytes; return r; };
    half_t* Wg0 = (half_t*)take((size_t)256 * 160 * 2);
    half_t* Wg1 = (half_t*)take((size_t)256 * 256 * 2);
    half_t* Wg2 = (half_t*)take((size_t)256 * 256 * 2);
    half_t* Wg3 = (half_t*)take((size_t)32 * 256 * 2);
    half_t* W0  = (half_t*)take((size_t)8 * 256 * 160 * 2);
    half_t* W1  = (half_t*)take((size_t)8 * 256 * 288 * 2);
    half_t* W2  = (half_t*)take((size_t)8 * 128 * 288 * 2);
    float* out  = (float*)d_out;

    WPack pk;
    int blk = 0;
    auto mk = [&](int i, const float* s, half_t* dst, int K, int N, int Npad, int E) {
        pk.d[i] = WDesc{s, dst, K, N, Npad, blk};
        blk += E * (K / 32) * (Npad / 32);
    };
    mk(0, gw0, Wg0, 160, 256, 256, 1);
    mk(1, gw1, Wg1, 256, 256, 256, 1);
    mk(2, gw2, Wg2, 256, 256, 256, 1);
    mk(3, gw3, Wg3, 256, 8, 32, 1);
    mk(4, w0, W0, 160, 256, 256, 8);
    mk(5, w1, W1, 288, 256, 256, 8);
    mk(6, w2, W2, 288, 128, 128, 8);

    hipFuncSetAttribute((const void*)fused_mann,
                        hipFuncAttributeMaxDynamicSharedMemorySize, SMEM_BYTES);

    conv_w_all<<<dim3(blk), dim3(256), 0, stream>>>(pk);
    fused_mann<<<dim3(BSZ / 32), dim3(NT), SMEM_BYTES, stream>>>(
        x, z, Wg0, Wg1, Wg2, Wg3, gb0, gb1, gb2, gb3,
        W0, W1, W2, b0, b1, b2, out);
}

// Round 6
// 130.506 us; speedup vs baseline: 1.1186x; 1.0063x over previous
//
#include <hip/hip_runtime.h>
#include <hip/hip_bf16.h>

typedef _Float16 half_t;
typedef __attribute__((ext_vector_type(8))) _Float16 half8;
typedef __attribute__((ext_vector_type(4))) _Float16 half4;
typedef __attribute__((ext_vector_type(4))) float float4v;
typedef __attribute__((ext_vector_type(2))) float float2v;

#define BSZ 8192
#define NT 1024   // 16 waves, grid 256 = 1 block/CU
#define ACTSTR 280  // act stride (halfs): 560B, 16B-aligned, 2-way banks max
#define XSTR 152    // x stride: 304B
#define ZSTR 40     // z stride: 80B

// ---- dynamic LDS layout (half_t units unless noted) ----
#define OFF_SX 0
#define OFF_SB0 (OFF_SX + 32 * XSTR)
#define OFF_SB1 (OFF_SB0 + 32 * ACTSTR)
#define OFF_SZ (OFF_SB1 + 32 * ACTSTR)
#define HALFS_TOTAL (OFF_SZ + 32 * ZSTR)   // 24064 halfs = 48128 B
#define OFF_LOG_B (HALFS_TOTAL * 2)
#define OFF_CF_B (OFF_LOG_B + 1024)
// r4 LESSON: the backend budgets VGPRs from the LDS-derived occupancy bound.
// PAD dynamic LDS past 80KB so the bound says 1 block/CU -> 4 waves/SIMD ->
// 128-VGPR budget. (attributes alone did NOT override the heuristic, r2/r3.)
// r6: the 3-stage pipeline needs ~90 live VGPRs — this pad is load-bearing.
#define SMEM_BYTES 131072

__device__ __forceinline__ float elu_fast(float v) {
    return v > 0.f ? v : (__expf(v) - 1.f);
}

// W layout (validated r14): frag-ordered 1KB blocks [e][strip][chunk][512 halfs],
// block[(quad*16+l15)*8+j] = W[n=strip*16+l15][k=chunk*32+quad*8+j]. A lane's
// B fragment is 16B at base + lane*16B -> one coalesced global_load_dwordx4.
//
// r4 LESSON: zero-slack issue->use = correlated all-wave stalls (MfmaUtil+
// VALUBusy < 50%, no pipe BW-saturated). r5: depth-1 ping-pong -> 60->50.5us.
// r5 post-mortem: body wall ~224cy, depth-1 slack ~224cy covers L2-hit
// (~200-300cy) marginally but not L3 (~400-600cy; 8 XCDs each pull their own
// weight copy — FETCH 13.6MB vs 2.8MB unique). r6: depth-2 slack via 3-stage
// rotation (S0/S1/S2, unroll-3 steady loop, guarded drain) -> ~450cy slack on
// both the global B loads and the LDS A reads. All register indices static.
template <int EXPP, int NPASS, int CH, int MT, bool ZLAST, int ACT, int DST>
__device__ __forceinline__ void layer_run(
    const half_t* sSrc, int sstr, const half_t* sZ,
    const half_t* __restrict__ W, int NS,
    const float* __restrict__ bias, int biasN, const float* sCf,
    half_t* sDst, float* __restrict__ gOut, int ldg,
    int row0, int strip, int mrow, int lane, int l15, int quad) {
    constexpr int TOT = NPASS * CH;
    static_assert(TOT >= 2, "pipeline prologue needs >= 2 bodies");
    const size_t estr = (size_t)NS * CH * 512;  // halfs per expert in layout
    const int col = strip * 16 + l15;
    const half_t* aBase = sSrc + (mrow + l15) * sstr + quad * 8;
    const half_t* zBase = sZ + (mrow + l15) * ZSTR + quad * 8;

    // issue-side state (walks chunk-by-chunk through the frag-ordered layout)
    const half_t* wp = W + (size_t)strip * CH * 512 + lane * 8;
    int c_i = 0;
    // compute-side state
    const float* bp = bias + col;
    int c_c = 0, h_c = 0;

    half8 B0[EXPP], B1[EXPP], B2[EXPP], A0[MT], A1[MT], A2[MT];
    float part[MT][4];
    float bv[EXPP];
    float4v acc[EXPP][MT];

    auto issue = [&](half8(&B)[EXPP], half8(&A)[MT]) {
#pragma unroll
        for (int e = 0; e < EXPP; ++e) B[e] = *(const half8*)&wp[(size_t)e * estr];
#pragma unroll
        for (int mt = 0; mt < MT; ++mt)
            A[mt] = (ZLAST && c_i == CH - 1)
                        ? *(const half8*)&zBase[mt * 16 * ZSTR]
                        : *(const half8*)&aBase[mt * 16 * sstr + c_i * 32];
        wp += 512;
        if (++c_i == CH) { c_i = 0; wp += (size_t)EXPP * estr - (size_t)CH * 512; }
    };

    auto body = [&](half8(&B)[EXPP], half8(&A)[MT]) {
        if (c_c == 0) {
#pragma unroll
            for (int e = 0; e < EXPP; ++e) bv[e] = bp[(size_t)e * biasN];
#pragma unroll
            for (int e = 0; e < EXPP; ++e)
#pragma unroll
                for (int mt = 0; mt < MT; ++mt) acc[e][mt] = (float4v){0.f, 0.f, 0.f, 0.f};
        }
#pragma unroll
        for (int e = 0; e < EXPP; ++e)
#pragma unroll
            for (int mt = 0; mt < MT; ++mt)
                acc[e][mt] = __builtin_amdgcn_mfma_f32_16x16x32_f16(A[mt], B[e], acc[e][mt], 0, 0, 0);
        if (c_c == CH - 1) {  // pass-h_c epilogue
#pragma unroll
            for (int mt = 0; mt < MT; ++mt)
#pragma unroll
                for (int r = 0; r < 4; ++r) {
                    const int rl = mrow + mt * 16 + quad * 4 + r;
                    float val;
                    if constexpr (EXPP * NPASS == 1) {
                        val = acc[0][mt][r] + bv[0];
                    } else {
                        const float2v cf = *(const float2v*)&sCf[rl * 8 + h_c * EXPP];  // EXPP==2
                        val = cf[0] * (acc[0][mt][r] + bv[0]);
                        val += cf[1] * (acc[1][mt][r] + bv[1]);
                    }
                    part[mt][r] = (h_c == 0) ? val : part[mt][r] + val;
                    if (h_c == NPASS - 1) {
                        float o = part[mt][r];
                        if (DST == 0) {
                            if (ACT) o = elu_fast(o);
                            sDst[rl * ACTSTR + col] = (half_t)o;
                        } else {
                            gOut[(size_t)(row0 + rl) * ldg + col] = o;
                        }
                    }
                }
            bp += (size_t)EXPP * biasN;
        }
        if (++c_c == CH) { c_c = 0; ++h_c; }
    };

    // ---- 3-stage software pipeline: issue body i+2 while consuming body i ----
    issue(B0, A0);  // body 0
    issue(B1, A1);  // body 1
    int it = 0;
#pragma unroll 1
    for (; it + 5 <= TOT; it += 3) {   // guard: deepest issue inside is it+4
        issue(B2, A2);  body(B0, A0);  // issue it+2, consume it
        issue(B0, A0);  body(B1, A1);  // issue it+3, consume it+1
        issue(B1, A1);  body(B2, A2);  // issue it+4, consume it+2
    }
    // drain: R = TOT - it in [2,4]; S0=body it, S1=body it+1 in flight
    {
        const int R = TOT - it;
        if (R == 2) {
            body(B0, A0); body(B1, A1);
        } else if (R == 3) {
            issue(B2, A2); body(B0, A0); body(B1, A1); body(B2, A2);
        } else {  // R == 4
            issue(B2, A2); body(B0, A0);
            issue(B0, A0); body(B1, A1); body(B2, A2); body(B0, A0);
        }
    }
}

// Logits: N=8, wave 0 only. Wg3 in frag-block layout (NS=2, CH=8), strip 0.
__device__ __forceinline__ void layer_logits(
    const half_t* sSrc, const half_t* __restrict__ W,
    const float* __restrict__ bias, float* sLog, int wv, int lane, int l15, int quad) {
    if (wv != 0) return;
    float4v acc[2] = {(float4v){0.f, 0.f, 0.f, 0.f}, (float4v){0.f, 0.f, 0.f, 0.f}};
#pragma unroll
    for (int c = 0; c < 8; ++c) {
        half8 a0 = *(const half8*)&sSrc[l15 * ACTSTR + c * 32 + quad * 8];
        half8 a1 = *(const half8*)&sSrc[(16 + l15) * ACTSTR + c * 32 + quad * 8];
        half8 b = *(const half8*)&W[c * 512 + lane * 8];
        acc[0] = __builtin_amdgcn_mfma_f32_16x16x32_f16(a0, b, acc[0], 0, 0, 0);
        acc[1] = __builtin_amdgcn_mfma_f32_16x16x32_f16(a1, b, acc[1], 0, 0, 0);
    }
    if (l15 < 8) {
        const float bvv = bias[l15];
#pragma unroll
        for (int mt = 0; mt < 2; ++mt)
#pragma unroll
            for (int r = 0; r < 4; ++r)
                sLog[(mt * 16 + quad * 4 + r) * 8 + l15] = acc[mt][r] + bvv;
    }
}

__global__ __launch_bounds__(NT) void fused_mann(
    const float* __restrict__ x, const float* __restrict__ z,
    const half_t* __restrict__ Wg0, const half_t* __restrict__ Wg1,
    const half_t* __restrict__ Wg2, const half_t* __restrict__ Wg3,
    const float* __restrict__ gb0, const float* __restrict__ gb1,
    const float* __restrict__ gb2, const float* __restrict__ gb3,
    const half_t* __restrict__ W0, const half_t* __restrict__ W1,
    const half_t* __restrict__ W2, const float* __restrict__ b0,
    const float* __restrict__ b1, const float* __restrict__ b2,
    float* __restrict__ out) {
    extern __shared__ __align__(16) char dynsm[];
    half_t* sm = (half_t*)dynsm;
    half_t* sX = sm + OFF_SX;
    half_t* sB0 = sm + OFF_SB0;
    half_t* sB1 = sm + OFF_SB1;
    half_t* sZ = sm + OFF_SZ;
    float* sLog = (float*)(dynsm + OFF_LOG_B);
    float* sCf = (float*)(dynsm + OFF_CF_B);

    const int tid = threadIdx.x;
    const int row0 = blockIdx.x * 32;
    const int lane = tid & 63, wv = tid >> 6;  // 0..15
    const int l15 = lane & 15, quad = lane >> 4;

    for (int i = tid; i < 32 * 128; i += NT) {
        int r = i >> 7, c = i & 127;
        sX[r * XSTR + c] = (half_t)x[(size_t)(row0 + r) * 128 + c];
    }
    for (int i = tid; i < 32 * 32; i += NT) {
        int r = i >> 5, c = i & 31;
        sZ[r * ZSTR + c] = (half_t)z[(size_t)(row0 + r) * 32 + c];
    }
    __syncthreads();

    // Gating MLP (EXPP=1, 16 strips / 16 waves, MT=2)
    layer_run<1, 1, 5, 2, true, 1, 0>(sX, XSTR, sZ, Wg0, 16, gb0, 256, nullptr,
                                      sB0, nullptr, 0, row0, wv, 0, lane, l15, quad);
    __syncthreads();
    layer_run<1, 1, 8, 2, false, 1, 0>(sB0, ACTSTR, sZ, Wg1, 16, gb1, 256, nullptr,
                                       sB1, nullptr, 0, row0, wv, 0, lane, l15, quad);
    __syncthreads();
    layer_run<1, 1, 8, 2, false, 1, 0>(sB1, ACTSTR, sZ, Wg2, 16, gb2, 256, nullptr,
                                       sB0, nullptr, 0, row0, wv, 0, lane, l15, quad);
    __syncthreads();
    layer_logits(sB0, Wg3, gb3, sLog, wv, lane, l15, quad);
    __syncthreads();
    if (tid < 32) {
        float v[8], m = -1e30f;
#pragma unroll
        for (int e = 0; e < 8; ++e) { v[e] = sLog[tid * 8 + e]; m = fmaxf(m, v[e]); }
        float sum = 0.f;
#pragma unroll
        for (int e = 0; e < 8; ++e) { v[e] = __expf(v[e] - m); sum += v[e]; }
        float inv = 1.f / sum;
#pragma unroll
        for (int e = 0; e < 8; ++e) sCf[tid * 8 + e] = v[e] * inv;
    }
    __syncthreads();
    // Expert layers: 8 experts = 4 passes x 2
    layer_run<2, 4, 5, 2, true, 1, 0>(sX, XSTR, sZ, W0, 16, b0, 256, sCf,
                                      sB1, nullptr, 0, row0, wv, 0, lane, l15, quad);
    __syncthreads();
    layer_run<2, 4, 9, 2, true, 1, 0>(sB1, ACTSTR, sZ, W1, 16, b1, 256, sCf,
                                      sB0, nullptr, 0, row0, wv, 0, lane, l15, quad);
    __syncthreads();
    // Final: N=128 -> 8 strips x 2 m-halves over 16 waves (MT=1)
    layer_run<2, 4, 9, 1, true, 0, 2>(sB0, ACTSTR, sZ, W2, 8, b2, 128, sCf,
                                      nullptr, out, 128, row0, wv & 7, (wv >> 3) * 16,
                                      lane, l15, quad);
}

// Weight prep (validated r14): [E][K][N] fp32 -> frag-ordered fp16 1KB blocks
// dst[((e*NS + n/16)*CHN + k/32)*512 + ((k%32/8)*16 + n%16)*8 + k%8], zero-pad n>=N.
struct WDesc { const float* src; half_t* dst; int K, N, Npad, blk0; };
struct WPack { WDesc d[7]; };

__global__ __launch_bounds__(256) void conv_w_all(WPack pk) {
    __shared__ float t[32][33];
    const int bid = blockIdx.x;
    int di = 0;
#pragma unroll
    for (int i = 1; i < 7; ++i)
        if (bid >= pk.d[i].blk0) di = i;
    const WDesc d = pk.d[di];
    const int NS = d.Npad >> 4, CHN = d.K >> 5;
    const int ntiles = d.Npad / 32, ktiles = CHN;
    int local = bid - d.blk0;
    const int e = local / (ktiles * ntiles);
    local %= ktiles * ntiles;
    const int k0 = (local / ntiles) * 32, n0 = (local % ntiles) * 32;
    const int tr = threadIdx.x >> 3;        // 0..31
    const int tc = (threadIdx.x & 7) * 4;   // 0,4,..,28

    float4 v = {0.f, 0.f, 0.f, 0.f};
    if (n0 + tc < d.N)
        v = *(const float4*)&d.src[((size_t)e * d.K + k0 + tr) * d.N + n0 + tc];
    t[tr][tc] = v.x; t[tr][tc + 1] = v.y; t[tr][tc + 2] = v.z; t[tr][tc + 3] = v.w;
    __syncthreads();
    half4 h;
#pragma unroll
    for (int i = 0; i < 4; ++i) h[i] = (half_t)t[tc + i][tr];
    const int n = n0 + tr;
    const size_t blk = ((size_t)e * NS + (n >> 4)) * CHN + (k0 >> 5);
    const int off = ((tc >> 3) * 16 + (n & 15)) * 8 + (tc & 7);
    *(half4*)&d.dst[blk * 512 + off] = h;
}

extern "C" void kernel_launch(void* const* d_in, const int* in_sizes, int n_in,
                              void* d_out, int out_size, void* d_ws, size_t ws_size,
                              hipStream_t stream) {
    const float* x   = (const float*)d_in[0];
    const float* z   = (const float*)d_in[1];
    const float* gw0 = (const float*)d_in[2];
    const float* gb0 = (const float*)d_in[3];
    const float* gw1 = (const float*)d_in[4];
    const float* gb1 = (const float*)d_in[5];
    const float* gw2 = (const float*)d_in[6];
    const float* gb2 = (const float*)d_in[7];
    const float* gw3 = (const float*)d_in[8];
    const float* gb3 = (const float*)d_in[9];
    const float* w0  = (const float*)d_in[10];
    const float* b0  = (const float*)d_in[11];
    const float* w1  = (const float*)d_in[12];
    const float* b1  = (const float*)d_in[13];
    const float* w2  = (const float*)d_in[14];
    const float* b2  = (const float*)d_in[15];

    char* p = (char*)d_ws;
    auto take = [&](size_t bytes) { char* r = p; p += bytes; return r; };
    half_t* Wg0 = (half_t*)take((size_t)256 * 160 * 2);
    half_t* Wg1 = (half_t*)take((size_t)256 * 256 * 2);
    half_t* Wg2 = (half_t*)take((size_t)256 * 256 * 2);
    half_t* Wg3 = (half_t*)take((size_t)32 * 256 * 2);
    half_t* W0  = (half_t*)take((size_t)8 * 256 * 160 * 2);
    half_t* W1  = (half_t*)take((size_t)8 * 256 * 288 * 2);
    half_t* W2  = (half_t*)take((size_t)8 * 128 * 288 * 2);
    float* out  = (float*)d_out;

    WPack pk;
    int blk = 0;
    auto mk = [&](int i, const float* s, half_t* dst, int K, int N, int Npad, int E) {
        pk.d[i] = WDesc{s, dst, K, N, Npad, blk};
        blk += E * (K / 32) * (Npad / 32);
    };
    mk(0, gw0, Wg0, 160, 256, 256, 1);
    mk(1, gw1, Wg1, 256, 256, 256, 1);
    mk(2, gw2, Wg2, 256, 256, 256, 1);
    mk(3, gw3, Wg3, 256, 8, 32, 1);
    mk(4, w0, W0, 160, 256, 256, 8);
    mk(5, w1, W1, 288, 256, 256, 8);
    mk(6, w2, W2, 288, 128, 128, 8);

    hipFuncSetAttribute((const void*)fused_mann,
                        hipFuncAttributeMaxDynamicSharedMemorySize, SMEM_BYTES);

    conv_w_all<<<dim3(blk), dim3(256), 0, stream>>>(pk);
    fused_mann<<<dim3(BSZ / 32), dim3(NT), SMEM_BYTES, stream>>>(
        x, z, Wg0, Wg1, Wg2, Wg3, gb0, gb1, gb2, gb3,
        W0, W1, W2, b0, b1, b2, out);
}